// Round 1
// baseline (320.979 us; speedup 1.0000x reference)
//
#include <hip/hip_runtime.h>

#define HH 16
#define SS 4096
#define DHD 128
#define BR 64         // q rows per block (16 per wave)
#define BC 64         // k/v rows per tile
#define LDQ 144       // bf16/row for k_s (and Q staging overlay): 288B, 16B-aligned
#define LDV 68        // bf16/row for vt_s: 136B (b64 access, ~4-way)
#define LDPT 72       // bf16/row for pT_s: 144B (16B-aligned)
#define LDOS 136      // f32/row for epilogue overlay: 544B (16B-aligned)
#define DM  (HH * DHD)

typedef __bf16 bf16x8_t __attribute__((ext_vector_type(8)));
typedef __bf16 bf16x4_t __attribute__((ext_vector_type(4)));
typedef float  f32x4_t  __attribute__((ext_vector_type(4)));

// LDS-only barrier: drain lgkmcnt but leave global prefetch loads in flight
// (plain __syncthreads emits s_waitcnt vmcnt(0) which kills the prefetch).
#define BAR() asm volatile("s_waitcnt lgkmcnt(0)\n\ts_barrier" ::: "memory")

__device__ __forceinline__ f32x4_t vmax4(f32x4_t a, f32x4_t b) {
    f32x4_t r;
    r[0] = fmaxf(a[0], b[0]); r[1] = fmaxf(a[1], b[1]);
    r[2] = fmaxf(a[2], b[2]); r[3] = fmaxf(a[3], b[3]);
    return r;
}

__global__ __launch_bounds__(256, 3)
void fa_fwd(const float* __restrict__ q, const float* __restrict__ k,
            const float* __restrict__ v, float* __restrict__ out)
{
    // 1024 blocks, one q-tile each. qt = 63 - g: longest blocks dispatch first
    // (LPT scheduling; 4 blocks/CU average, 3 resident at 45KB LDS).
    const int L = blockIdx.x;
    const int h = L & 15;
    const int qt = 63 - (L >> 4);

    const int tid  = threadIdx.x;
    const int wave = tid >> 6;
    const int lane = tid & 63;
    const int l16  = lane & 15;
    const int quad = lane >> 4;
    const int rK   = tid >> 5;
    const int c4   = tid & 31;
    const int dbase = (wave & 1) * 64;
    const int rbase = (wave >> 1) * 32;

    // smem: [k/q 18432][vt 17408][pT 9216] = 45056 B.
    // Q staging overlays k_s: Q is read into registers before the first K commit.
    __shared__ __align__(16) char smem[45056];
    unsigned short* k_s  = (unsigned short*)smem;
    unsigned short* vt_s = (unsigned short*)(smem + 18432);
    unsigned short* pT_s = (unsigned short*)(smem + 35840);
    float* os = (float*)smem;   // epilogue overlay (34816 B over k+vt)

    const size_t hoff = (size_t)h * SS * DHD;
    const float* qh = q + hoff;
    const float* kh = k + hoff;
    const float* vh = v + hoff;

    float4 kreg[8];
    float  vreg[8][4];
    auto issue = [&](int j) {
        const float* kb = kh + (size_t)j * BC * DHD;
        #pragma unroll
        for (int i = 0; i < 8; ++i)
            kreg[i] = ((const float4*)(kb + (size_t)(rK + i * 8) * DHD))[c4];
        const float* vb = vh + (size_t)j * BC * DHD + dbase + lane;
        #pragma unroll
        for (int p = 0; p < 8; ++p) {
            const float* vp = vb + (size_t)(rbase + p * 4) * DHD;
            vreg[p][0] = vp[0];
            vreg[p][1] = vp[DHD];
            vreg[p][2] = vp[2 * DHD];
            vreg[p][3] = vp[3 * DHD];
        }
    };

    // 1/sqrt(128) * log2(e): softmax runs in the exp2 domain (v_exp_f32 is 2^x;
    // folding log2e here kills the per-exp v_mul).
    const float scale = 0.088388347648318447f * 1.4426950408889634f;
    issue(0);

    // ---- stage Q (scale folded) into k_s region ----
    #pragma unroll
    for (int i = 0; i < 8; ++i) {
        int idx = tid + i * 256;
        int r   = idx >> 5;
        int cc  = idx & 31;
        float4 val = ((const float4*)(qh + (size_t)(qt * BR + r) * DHD))[cc];
        bf16x4_t bb;
        bb[0] = (__bf16)(val.x * scale); bb[1] = (__bf16)(val.y * scale);
        bb[2] = (__bf16)(val.z * scale); bb[3] = (__bf16)(val.w * scale);
        *(bf16x4_t*)&k_s[r * LDQ + cc * 4] = bb;
    }
    __syncthreads();

    // ---- Q B-fragments (n-dim = wave's 16 q rows) ----
    bf16x8_t qf[4];
    #pragma unroll
    for (int kc = 0; kc < 4; ++kc)
        qf[kc] = *(const bf16x8_t*)
            &k_s[(wave * 16 + l16) * LDQ + kc * 32 + quad * 8];

    f32x4_t oacc[8];               // O^T: row=d (8 m-tiles), col=q=l16
    #pragma unroll
    for (int mt = 0; mt < 8; ++mt) oacc[mt] = (f32x4_t)(0.0f);
    float mi = -INFINITY, li = 0.0f;   // per-lane scalars (one q per lane), log2 domain

    const int q_local = wave * 16 + l16;

    for (int j = 0; j <= qt; ++j) {
        BAR();                     // prev LDS reads (incl. qf at j=0) drained; vm in flight
        // ---- commit prefetched K / V^T ----
        #pragma unroll
        for (int i = 0; i < 8; ++i) {
            bf16x4_t bb;
            bb[0] = (__bf16)kreg[i].x; bb[1] = (__bf16)kreg[i].y;
            bb[2] = (__bf16)kreg[i].z; bb[3] = (__bf16)kreg[i].w;
            *(bf16x4_t*)&k_s[(rK + i * 8) * LDQ + c4 * 4] = bb;
        }
        #pragma unroll
        for (int p = 0; p < 8; ++p) {
            bf16x4_t bb;
            bb[0] = (__bf16)vreg[p][0]; bb[1] = (__bf16)vreg[p][1];
            bb[2] = (__bf16)vreg[p][2]; bb[3] = (__bf16)vreg[p][3];
            *(bf16x4_t*)&vt_s[(dbase + lane) * LDV + rbase + p * 4] = bb;
        }
        if (j < qt) issue(j + 1);
        BAR();

        // ---- S^T = K Q^T : 4 m-tiles (k-dim) x 1 n-tile (q) ----
        f32x4_t sa[4];
        #pragma unroll
        for (int mt = 0; mt < 4; ++mt) sa[mt] = (f32x4_t)(0.0f);
        #pragma unroll
        for (int kc = 0; kc < 4; ++kc)
            #pragma unroll
            for (int mt = 0; mt < 4; ++mt) {
                bf16x8_t kf = *(const bf16x8_t*)
                    &k_s[(mt * 16 + l16) * LDQ + kc * 32 + quad * 8];
                sa[mt] = __builtin_amdgcn_mfma_f32_16x16x32_bf16(kf, qf[kc], sa[mt], 0, 0, 0);
            }

        // ---- causal mask (diag tile only): row=k=mt*16+quad*4+r, col=q=l16 ----
        if (j == qt) {
            #pragma unroll
            for (int mt = 0; mt < 4; ++mt)
                #pragma unroll
                for (int r = 0; r < 4; ++r)
                    if (mt * 16 + quad * 4 + r > q_local) sa[mt][r] = -INFINITY;
        }

        // ---- online softmax (exp2 domain): in-lane 16 + 2 shfls ----
        f32x4_t mv = vmax4(vmax4(sa[0], sa[1]), vmax4(sa[2], sa[3]));
        float mx = fmaxf(fmaxf(mv[0], mv[1]), fmaxf(mv[2], mv[3]));
        mx = fmaxf(mx, __shfl_xor(mx, 16));
        mx = fmaxf(mx, __shfl_xor(mx, 32));
        // defer-max (T13): if no lane's max grew past mi+8, skip rescale entirely.
        // P then bounded by 2^8=256 (bf16/f32 fine); first iter mi=-inf -> else path.
        const bool skip = __all((int)(mx <= mi + 8.0f)) != 0;
        const float mnew = skip ? mi : fmaxf(mi, mx);
        bf16x4_t pkv[4];
        #pragma unroll
        for (int mt = 0; mt < 4; ++mt) {
            #pragma unroll
            for (int r = 0; r < 4; ++r)
                sa[mt][r] = __builtin_amdgcn_exp2f(sa[mt][r] - mnew);
            pkv[mt][0] = (__bf16)sa[mt][0]; pkv[mt][1] = (__bf16)sa[mt][1];
            pkv[mt][2] = (__bf16)sa[mt][2]; pkv[mt][3] = (__bf16)sa[mt][3];
        }
        f32x4_t sv = sa[0] + sa[1] + sa[2] + sa[3];
        float rs = (sv[0] + sv[1]) + (sv[2] + sv[3]);
        rs += __shfl_xor(rs, 16);
        rs += __shfl_xor(rs, 32);
        if (skip) {
            li += rs;
        } else {
            float a = __builtin_amdgcn_exp2f(mi - mnew);
            mi = mnew;
            li = li * a + rs;
            // ---- rescale O^T by per-lane scalar alpha ----
            #pragma unroll
            for (int mt = 0; mt < 8; ++mt) {
                oacc[mt][0] *= a; oacc[mt][1] *= a;
                oacc[mt][2] *= a; oacc[mt][3] *= a;
            }
        }

        // ---- P (q-major) -> LDS: 4 x ds_write_b64, wave-local ----
        #pragma unroll
        for (int mt = 0; mt < 4; ++mt)
            *(bf16x4_t*)&pT_s[(wave * 16 + l16) * LDPT + mt * 16 + quad * 4] = pkv[mt];

        // ---- O^T += V^T P^T : 8 m-tiles (d) x 1 n-tile (q), k=64 ----
        #pragma unroll
        for (int kc = 0; kc < 2; ++kc) {
            bf16x8_t pb = *(const bf16x8_t*)
                &pT_s[(wave * 16 + l16) * LDPT + kc * 32 + quad * 8];
            #pragma unroll
            for (int mt = 0; mt < 8; ++mt) {
                bf16x4_t vlo = *(const bf16x4_t*)
                    &vt_s[(mt * 16 + l16) * LDV + kc * 32 + quad * 8];
                bf16x4_t vhi = *(const bf16x4_t*)
                    &vt_s[(mt * 16 + l16) * LDV + kc * 32 + quad * 8 + 4];
                bf16x8_t vf = __builtin_shufflevector(vlo, vhi, 0,1,2,3,4,5,6,7);
                oacc[mt] = __builtin_amdgcn_mfma_f32_16x16x32_bf16(vf, pb, oacc[mt], 0, 0, 0);
            }
        }
    }

    // ---- epilogue: O^T -> LDS overlay -> coalesced fp32 store ----
    __syncthreads();               // all frag reads done before overlay
    float inv = 1.0f / li;
    #pragma unroll
    for (int mt = 0; mt < 8; ++mt)
        #pragma unroll
        for (int r = 0; r < 4; ++r)
            os[(wave * 16 + l16) * LDOS + mt * 16 + quad * 4 + r] = oacc[mt][r] * inv;
    __syncthreads();
    #pragma unroll
    for (int p = 0; p < 8; ++p) {
        int row = p * 8 + rK;
        float4 f4 = *(const float4*)&os[row * LDOS + c4 * 4];
        *(float4*)&out[(size_t)(qt * BR + row) * DM + h * DHD + c4 * 4] = f4;
    }
}

extern "C" void kernel_launch(void* const* d_in, const int* in_sizes, int n_in,
                              void* d_out, int out_size, void* d_ws, size_t ws_size,
                              hipStream_t stream) {
    const float* q = (const float*)d_in[0];
    const float* k = (const float*)d_in[1];
    const float* v = (const float*)d_in[2];
    float* out = (float*)d_out;
    fa_fwd<<<dim3((SS / BR) * HH), dim3(256), 0, stream>>>(q, k, v, out);
}

// Round 3
// 305.599 us; speedup vs baseline: 1.0503x; 1.0503x over previous
//
#include <hip/hip_runtime.h>

#define HH 16
#define SS 4096
#define DHD 128
#define BR 64         // q rows per block (16 per wave)
#define BC 64         // k/v rows per tile
#define LDQ 136       // bf16/row for k_s (and Q staging): 272B = 17x16B -> 2-way banks on b128
#define LDV 72        // bf16/row for vt_s: 144B = 9x16B -> b128 reads, 2-way banks
#define LDPT 72       // bf16/row for pT_s: 144B (16B-aligned)
#define LDOS 136      // f32/row for epilogue overlay: 544B (16B-aligned)
#define DM  (HH * DHD)

typedef __bf16 bf16x8_t __attribute__((ext_vector_type(8)));
typedef __bf16 bf16x4_t __attribute__((ext_vector_type(4)));
typedef float  f32x4_t  __attribute__((ext_vector_type(4)));

// LDS-only barrier: drain lgkmcnt but leave global prefetch loads in flight
// (plain __syncthreads emits s_waitcnt vmcnt(0) which kills the prefetch).
#define BAR() asm volatile("s_waitcnt lgkmcnt(0)\n\ts_barrier" ::: "memory")

__device__ __forceinline__ f32x4_t vmax4(f32x4_t a, f32x4_t b) {
    f32x4_t r;
    r[0] = fmaxf(a[0], b[0]); r[1] = fmaxf(a[1], b[1]);
    r[2] = fmaxf(a[2], b[2]); r[3] = fmaxf(a[3], b[3]);
    return r;
}

// launch_bounds arg2: empirically VGPR cap = 256/arg (R1: arg=3 -> 84 + spills).
// arg=2 -> cap 128; kernel needs ~112 live regs (R0: exactly 128, no spill).
__global__ __launch_bounds__(256, 2)
void fa_fwd(const float* __restrict__ q, const float* __restrict__ k,
            const float* __restrict__ v, float* __restrict__ out)
{
    // 1024 blocks, one q-tile each. qt = 63 - g: longest blocks dispatch first
    // (LPT scheduling; 45KB LDS -> 3 blocks/CU resident).
    const int L = blockIdx.x;
    const int h = L & 15;
    const int qt = 63 - (L >> 4);

    const int tid  = threadIdx.x;
    const int wave = tid >> 6;
    const int lane = tid & 63;
    const int l16  = lane & 15;
    const int quad = lane >> 4;
    const int rK   = tid >> 5;
    const int c4   = tid & 31;
    const int dbase = (wave & 1) * 64;
    const int rbase = (wave >> 1) * 32;

    // smem: [k/q 17408][vt 18432][pT 9216] = 45056 B.
    // Q staging overlays k_s: Q is read into registers before the first K commit.
    __shared__ __align__(16) char smem[45056];
    unsigned short* k_s  = (unsigned short*)smem;
    unsigned short* vt_s = (unsigned short*)(smem + 17408);
    unsigned short* pT_s = (unsigned short*)(smem + 35840);
    float* os = (float*)smem;   // epilogue overlay (34816 B over k+vt)

    const size_t hoff = (size_t)h * SS * DHD;
    const float* qh = q + hoff;
    const float* kh = k + hoff;
    const float* vh = v + hoff;

    float4 kreg[8];
    float  vreg[8][4];
    auto issue = [&](int j) {
        const float* kb = kh + (size_t)j * BC * DHD;
        #pragma unroll
        for (int i = 0; i < 8; ++i)
            kreg[i] = ((const float4*)(kb + (size_t)(rK + i * 8) * DHD))[c4];
        const float* vb = vh + (size_t)j * BC * DHD + dbase + lane;
        #pragma unroll
        for (int p = 0; p < 8; ++p) {
            const float* vp = vb + (size_t)(rbase + p * 4) * DHD;
            vreg[p][0] = vp[0];
            vreg[p][1] = vp[DHD];
            vreg[p][2] = vp[2 * DHD];
            vreg[p][3] = vp[3 * DHD];
        }
    };

    // 1/sqrt(128) * log2(e): softmax runs in the exp2 domain (v_exp_f32 is 2^x;
    // folding log2e here kills the per-exp v_mul).
    const float scale = 0.088388347648318447f * 1.4426950408889634f;
    issue(0);

    // ---- stage Q (scale folded) into k_s region ----
    #pragma unroll
    for (int i = 0; i < 8; ++i) {
        int idx = tid + i * 256;
        int r   = idx >> 5;
        int cc  = idx & 31;
        float4 val = ((const float4*)(qh + (size_t)(qt * BR + r) * DHD))[cc];
        bf16x4_t bb;
        bb[0] = (__bf16)(val.x * scale); bb[1] = (__bf16)(val.y * scale);
        bb[2] = (__bf16)(val.z * scale); bb[3] = (__bf16)(val.w * scale);
        *(bf16x4_t*)&k_s[r * LDQ + cc * 4] = bb;
    }
    __syncthreads();

    // ---- Q B-fragments (n-dim = wave's 16 q rows) ----
    bf16x8_t qf[4];
    #pragma unroll
    for (int kc = 0; kc < 4; ++kc)
        qf[kc] = *(const bf16x8_t*)
            &k_s[(wave * 16 + l16) * LDQ + kc * 32 + quad * 8];

    f32x4_t oacc[8];               // O^T: row=d (8 m-tiles), col=q=l16
    #pragma unroll
    for (int mt = 0; mt < 8; ++mt) oacc[mt] = (f32x4_t)(0.0f);
    float mi = -INFINITY, li = 0.0f;   // per-lane scalars (one q per lane), log2 domain

    const int q_local = wave * 16 + l16;

    for (int j = 0; j <= qt; ++j) {
        BAR();                     // prev LDS reads (incl. qf at j=0) drained; vm in flight
        // ---- commit prefetched K / V^T ----
        #pragma unroll
        for (int i = 0; i < 8; ++i) {
            bf16x4_t bb;
            bb[0] = (__bf16)kreg[i].x; bb[1] = (__bf16)kreg[i].y;
            bb[2] = (__bf16)kreg[i].z; bb[3] = (__bf16)kreg[i].w;
            *(bf16x4_t*)&k_s[(rK + i * 8) * LDQ + c4 * 4] = bb;
        }
        #pragma unroll
        for (int p = 0; p < 8; ++p) {
            bf16x4_t bb;
            bb[0] = (__bf16)vreg[p][0]; bb[1] = (__bf16)vreg[p][1];
            bb[2] = (__bf16)vreg[p][2]; bb[3] = (__bf16)vreg[p][3];
            *(bf16x4_t*)&vt_s[(dbase + lane) * LDV + rbase + p * 4] = bb;
        }
        if (j < qt) issue(j + 1);
        BAR();

        // ---- S^T = K Q^T : 4 m-tiles (k-dim) x 1 n-tile (q) ----
        f32x4_t sa[4];
        #pragma unroll
        for (int mt = 0; mt < 4; ++mt) sa[mt] = (f32x4_t)(0.0f);
        __builtin_amdgcn_s_setprio(1);
        #pragma unroll
        for (int kc = 0; kc < 4; ++kc)
            #pragma unroll
            for (int mt = 0; mt < 4; ++mt) {
                bf16x8_t kf = *(const bf16x8_t*)
                    &k_s[(mt * 16 + l16) * LDQ + kc * 32 + quad * 8];
                sa[mt] = __builtin_amdgcn_mfma_f32_16x16x32_bf16(kf, qf[kc], sa[mt], 0, 0, 0);
            }
        __builtin_amdgcn_s_setprio(0);

        // ---- causal mask (diag tile only): row=k=mt*16+quad*4+r, col=q=l16 ----
        if (j == qt) {
            #pragma unroll
            for (int mt = 0; mt < 4; ++mt)
                #pragma unroll
                for (int r = 0; r < 4; ++r)
                    if (mt * 16 + quad * 4 + r > q_local) sa[mt][r] = -INFINITY;
        }

        // ---- online softmax (exp2 domain): in-lane 16 + 2 shfls ----
        f32x4_t mv = vmax4(vmax4(sa[0], sa[1]), vmax4(sa[2], sa[3]));
        float mx = fmaxf(fmaxf(mv[0], mv[1]), fmaxf(mv[2], mv[3]));
        mx = fmaxf(mx, __shfl_xor(mx, 16));
        mx = fmaxf(mx, __shfl_xor(mx, 32));
        // defer-max (T13): if no lane's max grew past mi+8, skip rescale entirely.
        // P then bounded by 2^8=256 (bf16/f32 fine); first iter mi=-inf -> else path.
        const bool skip = __all((int)(mx <= mi + 8.0f)) != 0;
        const float mnew = skip ? mi : fmaxf(mi, mx);
        bf16x4_t pkv[4];
        #pragma unroll
        for (int mt = 0; mt < 4; ++mt) {
            #pragma unroll
            for (int r = 0; r < 4; ++r)
                sa[mt][r] = __builtin_amdgcn_exp2f(sa[mt][r] - mnew);
            pkv[mt][0] = (__bf16)sa[mt][0]; pkv[mt][1] = (__bf16)sa[mt][1];
            pkv[mt][2] = (__bf16)sa[mt][2]; pkv[mt][3] = (__bf16)sa[mt][3];
        }
        f32x4_t sv = sa[0] + sa[1] + sa[2] + sa[3];
        float rs = (sv[0] + sv[1]) + (sv[2] + sv[3]);
        rs += __shfl_xor(rs, 16);
        rs += __shfl_xor(rs, 32);
        if (skip) {
            li += rs;
        } else {
            float a = __builtin_amdgcn_exp2f(mi - mnew);
            mi = mnew;
            li = li * a + rs;
            // ---- rescale O^T by per-lane scalar alpha ----
            #pragma unroll
            for (int mt = 0; mt < 8; ++mt) {
                oacc[mt][0] *= a; oacc[mt][1] *= a;
                oacc[mt][2] *= a; oacc[mt][3] *= a;
            }
        }

        // ---- P (q-major) -> LDS: 4 x ds_write_b64, wave-local ----
        #pragma unroll
        for (int mt = 0; mt < 4; ++mt)
            *(bf16x4_t*)&pT_s[(wave * 16 + l16) * LDPT + mt * 16 + quad * 4] = pkv[mt];

        // ---- O^T += V^T P^T : 8 m-tiles (d) x 1 n-tile (q), k=64 ----
        __builtin_amdgcn_s_setprio(1);
        #pragma unroll
        for (int kc = 0; kc < 2; ++kc) {
            bf16x8_t pb = *(const bf16x8_t*)
                &pT_s[(wave * 16 + l16) * LDPT + kc * 32 + quad * 8];
            #pragma unroll
            for (int mt = 0; mt < 8; ++mt) {
                bf16x8_t vf = *(const bf16x8_t*)
                    &vt_s[(mt * 16 + l16) * LDV + kc * 32 + quad * 8];
                oacc[mt] = __builtin_amdgcn_mfma_f32_16x16x32_bf16(vf, pb, oacc[mt], 0, 0, 0);
            }
        }
        __builtin_amdgcn_s_setprio(0);
    }

    // ---- epilogue: O^T -> LDS overlay -> coalesced fp32 store ----
    __syncthreads();               // all frag reads done before overlay
    float inv = 1.0f / li;
    #pragma unroll
    for (int mt = 0; mt < 8; ++mt)
        #pragma unroll
        for (int r = 0; r < 4; ++r)
            os[(wave * 16 + l16) * LDOS + mt * 16 + quad * 4 + r] = oacc[mt][r] * inv;
    __syncthreads();
    #pragma unroll
    for (int p = 0; p < 8; ++p) {
        int row = p * 8 + rK;
        float4 f4 = *(const float4*)&os[row * LDOS + c4 * 4];
        *(float4*)&out[(size_t)(qt * BR + row) * DM + h * DHD + c4 * 4] = f4;
    }
}

extern "C" void kernel_launch(void* const* d_in, const int* in_sizes, int n_in,
                              void* d_out, int out_size, void* d_ws, size_t ws_size,
                              hipStream_t stream) {
    const float* q = (const float*)d_in[0];
    const float* k = (const float*)d_in[1];
    const float* v = (const float*)d_in[2];
    float* out = (float*)d_out;
    fa_fwd<<<dim3((SS / BR) * HH), dim3(256), 0, stream>>>(q, k, v, out);
}